// Round 16
// baseline (502.542 us; speedup 1.0000x reference)
//
#include <hip/hip_runtime.h>
#include <stdint.h>
#include <stddef.h>

#define NQS 8192
#define NKS 8192
#define DS  256

typedef _Float16 half8 __attribute__((ext_vector_type(8)));
typedef _Float16 half4v __attribute__((ext_vector_type(4)));
typedef float floatx16 __attribute__((ext_vector_type(16)));
typedef float floatx4e __attribute__((ext_vector_type(4)));
typedef uint32_t uint32x4 __attribute__((ext_vector_type(4)));

#define MFMA32(A,B,C) __builtin_amdgcn_mfma_f32_32x32x16_f16(A,B,C,0,0,0)

// async global->LDS 16B: dest = wave-uniform base + lane*16
#define GLOAD_LDS16(gp, lp) \
  __builtin_amdgcn_global_load_lds((const __attribute__((address_space(1))) void*)(gp), \
                                   (__attribute__((address_space(3))) void*)(lp), 16, 0, 0)

// 64-key tile = 16384 _Float16 ELEMENTS; 32-key subtile = 8192 (contiguous in Kc/Vc).
#define TILE_ELEMS 16384
#define SUB_ELEMS  8192

// ---------- mask dtype detection (int32 0/1 words OR to <=1; packed bytes don't) ----------
__global__ void detect_mask(const uint4* __restrict__ M, uint32_t* __restrict__ flag){
  __shared__ uint32_t s[256];
  uint32_t acc = 0;
  for (int i = threadIdx.x; i < 4096; i += 256){
    uint4 v = M[i];
    acc |= v.x | v.y | v.z | v.w;
  }
  s[threadIdx.x] = acc;
  __syncthreads();
  if (threadIdx.x == 0){
    uint32_t t = 0;
    for (int i = 0; i < 256; i++) t |= s[i];
    *flag = (t > 1u) ? 1u : 0u;   // 1 = bytes (uint8), 0 = int32
  }
}

// ---------- prep: Q->f16 row-major, K/V -> tiled 32x32x16 operand layouts ----------
__global__ void prep(const float* __restrict__ Qf, const float* __restrict__ K,
                     const float* __restrict__ V,
                     _Float16* __restrict__ Qh, _Float16* __restrict__ Kc,
                     _Float16* __restrict__ Vc){
  const int tid = threadIdx.x;
  if (blockIdx.x < 1024){
    size_t u = (size_t)blockIdx.x*256 + tid;       // 262144 units of 8 elems
    const float4* src = (const float4*)(Qf + u*8);
    float4 a = src[0], b = src[1];
    half8 h = {(_Float16)a.x,(_Float16)a.y,(_Float16)a.z,(_Float16)a.w,
               (_Float16)b.x,(_Float16)b.y,(_Float16)b.z,(_Float16)b.w};
    *(half8*)(Qh + u*8) = h;
  } else if (blockIdx.x < 2048){
    int gid = (blockIdx.x - 1024)*256 + tid;       // 262144
    int key = gid & 8191;
    int c   = gid >> 13;                           // 0..31
    int kt = c >> 1, t = c & 1;
    const float4* s = (const float4*)(K + (size_t)key*DS + kt*16 + t*8);
    float4 x = s[0], y = s[1];
    half8 h = {(_Float16)x.x,(_Float16)x.y,(_Float16)x.z,(_Float16)x.w,
               (_Float16)y.x,(_Float16)y.y,(_Float16)y.z,(_Float16)y.w};
    int tile = key >> 6, mt = (key >> 5) & 1, k32 = key & 31;
    size_t off = (size_t)tile*TILE_ELEMS + (((mt*16 + kt)*2 + t)*32 + k32)*8;
    *(half8*)(Kc + off) = h;
  } else {
    int gid = (blockIdx.x - 2048)*256 + tid;       // 262144
    int d32 = gid & 31;
    int t   = (gid >> 5) & 1;
    int nt  = (gid >> 6) & 7;
    int kkt = (gid >> 9) & 3;
    int tile = gid >> 11;
    int d = nt*32 + d32;
    int kb8 = tile*64 + kkt*16 + t*8;
    half8 h;
    #pragma unroll
    for (int j=0;j<8;j++) h[j] = (_Float16)V[(size_t)(kb8 + j)*DS + d];
    *(half8*)(Vc + (size_t)gid*8) = h;
  }
}

// ---------- main flash kernel: 32x32x16 MFMA, S^T trick, BK=32 ----------
// grid 512 = 64 row-groups(128) x 8 key-slices(1024); LDS 80 KB -> 2 blocks/CU.
// int32 mask: software-pipelined slab prefetch — slab s NT-loaded into regs at
// iter s-3, packed to the 16 KB LDS Pk table at iter s-2, consumed at 2s/2s+1.
// The per-iter vmcnt(0) barrier drain lands >=1 full iteration after issue
// (>900cyc HBM latency) so the 256 MB mask stream hides under the K-loop
// (R14's failure was a same-iteration issue->drain). Byte mode: R15 burst.
__global__ __launch_bounds__(256, 2) void attn_fwd(
  const _Float16* __restrict__ Qh, const _Float16* __restrict__ Kc,
  const _Float16* __restrict__ Vc, const uint8_t* __restrict__ Msk,
  const uint32_t* __restrict__ flag, _Float16* __restrict__ Oph,
  float* __restrict__ Lo)
{
  __shared__ _Float16 Kls[2][SUB_ELEMS];   // 32 KB: [buf][(kt*2+t)][key32][8]
  __shared__ _Float16 Vls[2][SUB_ELEMS];   // 32 KB: [buf][((kkt*8+nt)*2+t)][d32][8]
  __shared__ uint8_t  Pk[16][128][8];      // 16 KB: [slab][row][n]; nib(even)|nib(odd)<<4

  const int tid  = threadIdx.x;
  const int w    = tid >> 6;
  const int lane = tid & 63;
  const int q32  = lane & 31;
  const int t    = lane >> 5;
  const int b    = blockIdx.x;
  const int kh   = b & 7;                  // key slice (XCD-affine)
  const int rb   = (b >> 3)*128;
  const int rowbase = rb + w*32;
  const int sub0 = kh << 5;                // first 32-key subtile (kh*32)
  const int kbase = kh << 10;              // first key (kh*1024)

  const float kLog = 0.09016844005556021f; // (1/16) * log2(e)
  const float MFIX = 6.0f;

  const bool bm = (*flag != 0u);
  const uint32_t* M32 = (const uint32_t*)Msk;
  const uint32_t* mbase32 = M32 + (size_t)(rb + (tid>>3))*NKS + kbase + (tid&7)*4;
  const size_t mrowstride = (size_t)32*NKS;   // jj row step

  // ---- issue subtile-0 staging first (drains during mask prologue) ----
  {
    const size_t base = (size_t)sub0 * SUB_ELEMS;
    #pragma unroll
    for (int j=0;j<4;j++){
      int c = w*4 + j;
      GLOAD_LDS16(Kc + base + c*512 + lane*8, &Kls[0][c*512]);
      GLOAD_LDS16(Vc + base + c*512 + lane*8, &Vls[0][c*512]);
    }
  }

  uint32x4 B[8];   // pipelined slab reg buffer (32 VGPRs), int32 mode only
  if (!bm){
    // pack slabs 0,1 now; issue slab 2 into B.
    #pragma unroll
    for (int sp=0; sp<2; ++sp){
      uint32x4 e[4], o[4];
      #pragma unroll
      for (int jj=0;jj<4;jj++){
        const uint32_t* p = mbase32 + jj*mrowstride + sp*64;
        e[jj] = __builtin_nontemporal_load((const uint32x4*)p);
        o[jj] = __builtin_nontemporal_load((const uint32x4*)(p + 32));
      }
      #pragma unroll
      for (int jj=0;jj<4;jj++){
        uint8_t ne = (uint8_t)((e[jj][0]?1u:0u)|(e[jj][1]?2u:0u)|(e[jj][2]?4u:0u)|(e[jj][3]?8u:0u));
        uint8_t no = (uint8_t)((o[jj][0]?1u:0u)|(o[jj][1]?2u:0u)|(o[jj][2]?4u:0u)|(o[jj][3]?8u:0u));
        Pk[sp][jj*32 + (tid>>3)][tid&7] = (uint8_t)(ne | (no << 4));
      }
    }
    #pragma unroll
    for (int jj=0;jj<4;jj++){
      const uint32_t* p = mbase32 + jj*mrowstride + 2*64;
      B[jj*2]   = __builtin_nontemporal_load((const uint32x4*)p);
      B[jj*2+1] = __builtin_nontemporal_load((const uint32x4*)(p + 32));
    }
  } else {
    // byte mode (fallback): full 128 KB burst as in R15
    const uint8_t* mrow = Msk + (size_t)(rb + (tid>>1))*NKS + kbase + (tid&1)*16;
    #pragma unroll 1
    for (int sp=0; sp<16; ++sp){
      uint32x4 e = __builtin_nontemporal_load((const uint32x4*)(mrow + sp*64));
      uint32x4 o = __builtin_nontemporal_load((const uint32x4*)(mrow + sp*64 + 32));
      #pragma unroll
      for (int q=0;q<4;q++){
        uint32_t xe = e[q], xo = o[q];
        uint8_t ne = (uint8_t)(((xe&0x000000FFu)?1u:0u)|((xe&0x0000FF00u)?2u:0u)|
                               ((xe&0x00FF0000u)?4u:0u)|((xe&0xFF000000u)?8u:0u));
        uint8_t no = (uint8_t)(((xo&0x000000FFu)?1u:0u)|((xo&0x0000FF00u)?2u:0u)|
                               ((xo&0x00FF0000u)?4u:0u)|((xo&0xFF000000u)?8u:0u));
        Pk[sp][tid>>1][(tid&1)*4 + q] = (uint8_t)(ne | (no << 4));
      }
    }
  }

  // Q B-frags from f16: n=lane&31, k=(lane>>5)*8+j
  half8 qf[16];
  {
    const _Float16* qrow = Qh + (size_t)(rowbase + q32)*DS;
    #pragma unroll
    for (int kt=0;kt<16;kt++)
      qf[kt] = *(const half8*)(qrow + kt*16 + t*8);
  }

  floatx16 O[8];
  #pragma unroll
  for (int nt=0;nt<8;nt++)
    #pragma unroll
    for (int i=0;i<16;i++) O[nt][i] = 0.f;
  float lsum = 0.f;

  __syncthreads();   // staging-0 DMA drained + Pk[0..1] complete

  #pragma unroll 1
  for (int it=0; it<32; ++it){
    const int buf = it & 1;

    if (it < 31){
      const size_t base = (size_t)(sub0 + it + 1) * SUB_ELEMS;
      #pragma unroll
      for (int j=0;j<4;j++){
        int c = w*4 + j;
        GLOAD_LDS16(Kc + base + c*512 + lane*8, &Kls[buf^1][c*512]);
        GLOAD_LDS16(Vc + base + c*512 + lane*8, &Vls[buf^1][c*512]);
      }
    }

    // consumer: one ds_read_b64 -> 4 nibble-pair bytes; select half by it&1
    const uint2 nq = *(const uint2*)&Pk[it>>1][w*32 + q32][0];
    const int sh = (it & 1) * 4;
    const uint32_t nib_s[4] = { (nq.x >> (8*t + sh))      & 0xFu,
                                (nq.x >> (16 + 8*t + sh)) & 0xFu,
                                (nq.y >> (8*t + sh))      & 0xFu,
                                (nq.y >> (16 + 8*t + sh)) & 0xFu };

    // ---- pipelined mask: pack slab it+2 from B; issue slab it+3 into B ----
    if (!bm && it <= 13){
      #pragma unroll
      for (int jj=0;jj<4;jj++){
        uint32x4 e = B[jj*2], o = B[jj*2+1];
        uint8_t ne = (uint8_t)((e[0]?1u:0u)|(e[1]?2u:0u)|(e[2]?4u:0u)|(e[3]?8u:0u));
        uint8_t no = (uint8_t)((o[0]?1u:0u)|(o[1]?2u:0u)|(o[2]?4u:0u)|(o[3]?8u:0u));
        Pk[it+2][jj*32 + (tid>>3)][tid&7] = (uint8_t)(ne | (no << 4));
      }
      if (it <= 12){
        #pragma unroll
        for (int jj=0;jj<4;jj++){
          const uint32_t* p = mbase32 + jj*mrowstride + (it+3)*64;
          B[jj*2]   = __builtin_nontemporal_load((const uint32x4*)p);
          B[jj*2+1] = __builtin_nontemporal_load((const uint32x4*)(p + 32));
        }
      }
    }

    // ---- S^T[key32][q32], two 8-deep chains ----
    floatx16 S0, S1;
    #pragma unroll
    for (int i=0;i<16;i++){ S0[i]=0.f; S1[i]=0.f; }
    #pragma unroll
    for (int kt=0;kt<8;kt++){
      half8 kA = *(const half8*)&Kls[buf][((kt*2 + t)*32 + q32)*8];
      S0 = MFMA32(kA, qf[kt], S0);
    }
    #pragma unroll
    for (int kt=8;kt<16;kt++){
      half8 kA = *(const half8*)&Kls[buf][((kt*2 + t)*32 + q32)*8];
      S1 = MFMA32(kA, qf[kt], S1);
    }

    // ---- p = exp2(S*kLog - MFIX) masked; pack to f16x2 by s-group ----
    uint32_t pk[4][2];
    #pragma unroll
    for (int s=0;s<4;s++){
      float pv[4];
      #pragma unroll
      for (int rr=0;rr<4;rr++){
        int i = s*4 + rr;          // C-row = key = rr + 8s + 4t = nibble(2s+t) bit rr
        float e = __builtin_amdgcn_exp2f(__builtin_fmaf(S0[i]+S1[i], kLog, -MFIX));
        float p = ((nib_s[s] >> rr) & 1u) ? e : 0.f;
        lsum += p;
        pv[rr] = p;
      }
      pk[s][0] = __builtin_bit_cast(uint32_t, __builtin_amdgcn_cvt_pkrtz(pv[0], pv[1]));
      pk[s][1] = __builtin_bit_cast(uint32_t, __builtin_amdgcn_cvt_pkrtz(pv[2], pv[3]));
    }

    // ---- PV: per 16-key k-tile, assemble A-frag via half-wave exchange ----
    #pragma unroll
    for (int kt2=0; kt2<2; ++kt2){
      const int s_own  = kt2*2 + t;
      const int s_send = kt2*2 + (t^1);
      uint32_t r0 = __shfl_xor(__builtin_bit_cast(int, pk[s_send][0]), 32);
      uint32_t r1 = __shfl_xor(__builtin_bit_cast(int, pk[s_send][1]), 32);
      uint32_t lo0 = (t==0) ? pk[s_own][0] : r0;
      uint32_t lo1 = (t==0) ? pk[s_own][1] : r1;
      uint32_t hi0 = (t==0) ? r0 : pk[s_own][0];
      uint32_t hi1 = (t==0) ? r1 : pk[s_own][1];
      uint4 u = {lo0, lo1, hi0, hi1};
      half8 pa = __builtin_bit_cast(half8, u);
      #pragma unroll
      for (int nt=0;nt<8;nt++){
        half8 vB = *(const half8*)&Vls[buf][(((kt2*8+nt)*2 + t)*32 + q32)*8];
        O[nt] = MFMA32(pa, vB, O[nt]);
      }
    }

    __syncthreads();   // readers done with buf; staging + Pk writes ordered
  }

  // ---- epilogue: f16 partials, non-temporal (write-once stream) ----
  lsum += __builtin_bit_cast(float, __shfl_xor(__builtin_bit_cast(int, lsum), 32));
  if (t == 0) __builtin_nontemporal_store(lsum, &Lo[(size_t)b*128 + w*32 + q32]);

  _Float16* ob = Oph + ((size_t)b*128 + w*32)*256;
  #pragma unroll
  for (int nt=0;nt<8;nt++){
    #pragma unroll
    for (int i=0;i<16;i++){
      int row = (i&3) + 8*(i>>2) + 4*t;
      __builtin_nontemporal_store((_Float16)O[nt][i], &ob[(size_t)row*256 + nt*32 + q32]);
    }
  }
}

// ---------- cross-block combine of the 8 key-slices (plain sums, f16 partials) ----------
__global__ void combine8(const _Float16* __restrict__ Oph, const float* __restrict__ Lo,
                         float* __restrict__ Out){
  int gid = blockIdx.x*256 + threadIdx.x;   // 524288 threads, one float4 each
  int row = gid >> 6;
  int c4  = (gid & 63) << 2;
  int g   = row >> 7, r = row & 127;

  float lt = 0.f;
  #pragma unroll
  for (int kh=0;kh<8;kh++) lt += __builtin_nontemporal_load(&Lo[(size_t)(g*8 + kh)*128 + r]);
  float li = 1.0f / lt;

  floatx4e acc = {0.f,0.f,0.f,0.f};
  #pragma unroll
  for (int kh=0;kh<8;kh++){
    half4v o = __builtin_nontemporal_load(
        (const half4v*)(Oph + ((size_t)(g*8 + kh)*128 + r)*256 + c4));
    acc[0] += (float)o[0]; acc[1] += (float)o[1];
    acc[2] += (float)o[2]; acc[3] += (float)o[3];
  }
  acc[0] *= li; acc[1] *= li; acc[2] *= li; acc[3] *= li;
  __builtin_nontemporal_store(acc, (floatx4e*)(Out + (size_t)row*DS + c4));
}

extern "C" void kernel_launch(void* const* d_in, const int* in_sizes, int n_in,
                              void* d_out, int out_size, void* d_ws, size_t ws_size,
                              hipStream_t stream){
  (void)in_sizes; (void)n_in; (void)out_size; (void)ws_size;
  const float*   K = (const float*)d_in[0];
  const float*   V = (const float*)d_in[1];
  const float*   Q = (const float*)d_in[2];
  const uint8_t* M = (const uint8_t*)d_in[3];
  float* Out = (float*)d_out;

  _Float16* Qh  = (_Float16*)d_ws;                        // 4 MiB
  _Float16* Kc  = Qh + (size_t)NQS*DS;                    // 4 MiB
  _Float16* Vc  = Kc + (size_t)NKS*DS;                    // 4 MiB
  _Float16* Oph = Vc + (size_t)NKS*DS;                    // 32 MiB (512 blocks x 128x256 f16)
  float*    Lo  = (float*)(Oph + (size_t)512*128*256);    // 256 KiB
  uint32_t* flag = (uint32_t*)(Lo + 512*128);             // 4 B

  hipLaunchKernelGGL(detect_mask, dim3(1),    dim3(256), 0, stream, (const uint4*)M, flag);
  hipLaunchKernelGGL(prep,        dim3(3072), dim3(256), 0, stream, Q, K, V, Qh, Kc, Vc);
  hipLaunchKernelGGL(attn_fwd,    dim3(512),  dim3(256), 0, stream, Qh, Kc, Vc, M, flag, Oph, Lo);
  hipLaunchKernelGGL(combine8,    dim3(2048), dim3(256), 0, stream, Oph, Lo, Out);
}